// Round 10
// baseline (650.161 us; speedup 1.0000x reference)
//
#include <hip/hip_runtime.h>

#define N_TOK 16384
#define N_EMB 8192
#define DIM   512

typedef __attribute__((ext_vector_type(8))) short bf16x8;
typedef __attribute__((ext_vector_type(16))) float f32x16;
typedef unsigned short u16;

__device__ __forceinline__ u16 f2bf(float f) {
    unsigned u = __float_as_uint(f);
    u += 0x7fffu + ((u >> 16) & 1u);
    return (u16)(u >> 16);
}
__device__ __forceinline__ float bf2f(u16 h) {
    return __uint_as_float(((unsigned)h) << 16);
}

__device__ __forceinline__ void gload16(const void* g, void* l) {
    __builtin_amdgcn_global_load_lds(
        (const __attribute__((address_space(1))) unsigned int*)g,
        (__attribute__((address_space(3))) unsigned int*)l, 16, 0, 0);
}

// ---- prep: COLUMN-BLOCK panels: [panel 128 rows][kb 16][octet 8][row 128][8 u16]
//      octets 0-3 = hi granules (dims kb*32 + oct*8 ..+7), 4-7 = lo granules.
//      panel stride = 131072 u16 (256 KiB).
__global__ void prep_x_kernel(const float* __restrict__ x, u16* __restrict__ xint) {
    const int t = threadIdx.x;
    const int panel = blockIdx.x;            // 128 panels
    const int sub = t & 3;                   // row quarter (32 rows)
    const int unit = t >> 2;                 // 0..63
    const int kb = unit >> 2, g = unit & 3;
    const float* src0 = x + ((size_t)(panel * 128 + sub * 32)) * DIM + kb * 32 + g * 8;
    u16* dh = xint + (size_t)panel * 131072 + kb * 8192 + g * 1024 + sub * 256;
    u16* dl = dh + 4096;                     // +4 octets
#pragma unroll 4
    for (int i = 0; i < 32; ++i) {
        const float* s = src0 + (size_t)i * DIM;
        float4 v0 = *(const float4*)s;
        float4 v1 = *(const float4*)(s + 4);
        float vv[8] = {v0.x, v0.y, v0.z, v0.w, v1.x, v1.y, v1.z, v1.w};
        bf16x8 hv, lv;
#pragma unroll
        for (int j = 0; j < 8; ++j) {
            u16 h = f2bf(vv[j]);
            hv[j] = (short)h;
            lv[j] = (short)f2bf(vv[j] - bf2f(h));
        }
        *(bf16x8*)(dh + i * 8) = hv;
        *(bf16x8*)(dl + i * 8) = lv;
    }
}

__global__ void prep_w_kernel(const float* __restrict__ w, u16* __restrict__ wint) {
    const int t = threadIdx.x;
    const int panel = blockIdx.x;            // 64 panels
    const int sub = t & 3;
    const int unit = t >> 2;
    const int kb = unit >> 2, g = unit & 3;
    const float* src0 = w + ((size_t)(panel * 128 + sub * 32)) * DIM + kb * 32 + g * 8;
    u16* dh = wint + (size_t)panel * 131072 + kb * 8192 + g * 1024 + sub * 256;
    u16* dl = dh + 4096;
#pragma unroll 4
    for (int i = 0; i < 32; ++i) {
        const float* s = src0 + (size_t)i * DIM;
        float4 v0 = *(const float4*)s;
        float4 v1 = *(const float4*)(s + 4);
        float vv[8] = {v0.x, v0.y, v0.z, v0.w, v1.x, v1.y, v1.z, v1.w};
        bf16x8 hv, lv;
#pragma unroll
        for (int j = 0; j < 8; ++j) {
            u16 h = f2bf(vv[j]);
            hv[j] = (short)h;
            lv[j] = (short)f2bf(vv[j] - bf2f(h));
        }
        *(bf16x8*)(dh + i * 8) = hv;
        *(bf16x8*)(dl + i * 8) = lv;
    }
}

__global__ void wsq_kernel(const float* __restrict__ w, float* __restrict__ wsq) {
    const int tid = threadIdx.x, lane = tid & 63, wvi = tid >> 6;
    const int row = blockIdx.x * 4 + wvi;
    const float* src = w + (size_t)row * DIM + lane * 8;
    float4 v0 = *(const float4*)src;
    float4 v1 = *(const float4*)(src + 4);
    float s = v0.x * v0.x + v0.y * v0.y + v0.z * v0.z + v0.w * v0.w
            + v1.x * v1.x + v1.y * v1.y + v1.z * v1.z + v1.w * v1.w;
#pragma unroll
    for (int off = 1; off < 64; off <<= 1) s += __shfl_xor(s, off);
    if (lane == 0) wsq[row] = s;
}

// ---- main: 3-pass split-bf16 GEMM, 32x32x16 MFMA, m201 geometry:
//      block 512 thr (2wm x 4wn waves, wave tile 128x64), tile 256x256, BK=32.
//      Column-block LDS (conflict-free by contiguity, R9-proven) fed by
//      column-block GLOBAL layout (coalesced 1-KB staging chunks).
//      R5-proven counted-vmcnt double-buffer skeleton + setprio.
#define MFMA3(d, ah_, al_, bh_, bl_)                                          \
    do {                                                                      \
        d = __builtin_amdgcn_mfma_f32_32x32x16_bf16(ah_, bh_, d, 0, 0, 0);    \
        d = __builtin_amdgcn_mfma_f32_32x32x16_bf16(ah_, bl_, d, 0, 0, 0);    \
        d = __builtin_amdgcn_mfma_f32_32x32x16_bf16(al_, bh_, d, 0, 0, 0);    \
    } while (0)

__global__ __launch_bounds__(512, 1)
void gemm_argmin_kernel(const u16* __restrict__ xint, const u16* __restrict__ wint,
                        const float* __restrict__ wsq,
                        float* __restrict__ wsval, int* __restrict__ wsidx) {
    __shared__ u16 sm[2][32768];   // [buf][A 16384 | B 16384] = 128 KiB
    const int tid = threadIdx.x;
    const int lane = tid & 63, wv = tid >> 6;   // 8 waves
    const int wm = wv >> 2, wn = wv & 3;        // 2 x 4
    const int l31 = lane & 31, l5 = lane >> 5;

    // bijective XCD-aware decode: 2048 blocks; each XCD owns 4 (by,cs) pairs
    const int bid = blockIdx.x;
    const int xcd = bid & 7;
    const int q = bid >> 3;
    const int bx = q & 63;
    const int pair = ((q >> 6) << 3) | xcd;     // 0..31
    const int by = pair & 7, cs = pair >> 3;

    const int xp0 = bx * 2;                     // x panel base
    const int wp0 = cs * 16 + by * 2;           // w panel base
    const int colbase = cs * 2048 + by * 256;

    auto stage = [&](int t) {
        u16* buf = &sm[t & 1][0];
        const int kb = t;
#pragma unroll
        for (int j = 0; j < 4; ++j) {
            int a = wv * 4 + j;                 // 0..31, wave-uniform
            gload16(xint + (size_t)(xp0 + (a >> 4)) * 131072 + kb * 8192 + (a & 15) * 512 + lane * 8,
                    buf + a * 512);
            gload16(wint + (size_t)(wp0 + (a >> 4)) * 131072 + kb * 8192 + (a & 15) * 512 + lane * 8,
                    buf + 16384 + a * 512);
        }
    };

    // prologue: wq (oldest VMEM, drained by first vmcnt), stage tiles 0,1
    const float wq0 = wsq[colbase + wn * 64 + l31];
    const float wq1 = wsq[colbase + wn * 64 + 32 + l31];
    stage(0);
    stage(1);

    f32x16 acc[4][2];
#pragma unroll
    for (int mi = 0; mi < 4; ++mi)
#pragma unroll
        for (int ni = 0; ni < 2; ++ni)
#pragma unroll
            for (int qq = 0; qq < 16; ++qq) acc[mi][ni][qq] = 0.f;

    asm volatile("s_waitcnt vmcnt(8)" ::: "memory");   // wq + stage(0) retired
    __builtin_amdgcn_s_barrier();

    for (int t = 0; t < 16; ++t) {
        if (t > 0) {
            if (t == 15) asm volatile("s_waitcnt vmcnt(0)" ::: "memory");
            else         asm volatile("s_waitcnt vmcnt(8)" ::: "memory");
            __builtin_amdgcn_s_barrier();
        }
        const u16* base = &sm[t & 1][0];
#pragma unroll
        for (int kk = 0; kk < 2; ++kk) {
            const int oh = (2 * kk + l5) * 1024;        // hi octet offset (u16)
            bf16x8 ah[4], al[4], bh[2], bl[2];
#pragma unroll
            for (int mi = 0; mi < 4; ++mi) {
                const u16* p = base + wm * 8192 + oh + (mi * 32 + l31) * 8;
                ah[mi] = *(const bf16x8*)p;
                al[mi] = *(const bf16x8*)(p + 4096);    // lo octet = +4
            }
#pragma unroll
            for (int ni = 0; ni < 2; ++ni) {
                const u16* p = base + 16384 + (wn >> 1) * 8192 + oh
                             + ((wn & 1) * 64 + ni * 32 + l31) * 8;
                bh[ni] = *(const bf16x8*)p;
                bl[ni] = *(const bf16x8*)(p + 4096);
            }
            __builtin_amdgcn_s_setprio(1);
#pragma unroll
            for (int mi = 0; mi < 4; ++mi)
#pragma unroll
                for (int ni = 0; ni < 2; ++ni) {
                    MFMA3(acc[mi][ni], ah[mi], al[mi], bh[ni], bl[ni]);
                }
            __builtin_amdgcn_s_setprio(0);
        }
        asm volatile("s_waitcnt lgkmcnt(0)" ::: "memory");
        __builtin_amdgcn_sched_barrier(0);
        __builtin_amdgcn_s_barrier();
        if (t < 14) stage(t + 2);
    }

    // epilogue: score = wsq - 2*S ; per-wave col-reduce, block merge over wn
    float* mv  = (float*)&sm[0][0];                  // [4][256]
    int*   mi_ = (int*)((char*)&sm[0][0] + 4096);    // [4][256]
#pragma unroll
    for (int mi = 0; mi < 4; ++mi) {
#pragma unroll
        for (int qq = 0; qq < 16; ++qq) {
            const int i0 = colbase + wn * 64 + l31;
            float v = wq0 - 2.0f * acc[mi][0][qq];
            int ix = i0;
            float s1 = wq1 - 2.0f * acc[mi][1][qq];
            if (s1 < v) { v = s1; ix = i0 + 32; }
#pragma unroll
            for (int off = 1; off < 32; off <<= 1) {
                float ov = __shfl_xor(v, off);
                int   oi = __shfl_xor(ix, off);
                if (ov < v || (ov == v && oi < ix)) { v = ov; ix = oi; }
            }
            if (l31 == 0) {
                int rl = wm * 128 + mi * 32 + (qq & 3) + 8 * (qq >> 2) + 4 * l5;
                mv[wn * 256 + rl]  = v;
                mi_[wn * 256 + rl] = ix;
            }
        }
    }
    __syncthreads();
    if (tid < 256) {
        float v = mv[tid];
        int ix = mi_[tid];
#pragma unroll
        for (int k = 1; k < 4; ++k) {
            float v2 = mv[k * 256 + tid];
            int   i2 = mi_[k * 256 + tid];
            if (v2 < v || (v2 == v && i2 < ix)) { v = v2; ix = i2; }
        }
        const int tok = bx * 256 + tid;
        wsval[(size_t)tok * 32 + cs * 8 + by] = v;
        wsidx[(size_t)tok * 32 + cs * 8 + by] = ix;
    }
}

// ---------------- merge 32 partials + gather + loss partials ----------------
__global__ void gather_loss_kernel(const float* __restrict__ w, const float* __restrict__ x,
                                   const float* __restrict__ wsval, const int* __restrict__ wsidx,
                                   float* __restrict__ out, float* __restrict__ lossp) {
    const int tid = threadIdx.x, lane = tid & 63, wvi = tid >> 6;
    const int t = blockIdx.x * 4 + wvi;
    float v = 3.4e38f;
    int ix = 0x7fffffff;
    if (lane < 32) {
        v = wsval[(size_t)t * 32 + lane];
        ix = wsidx[(size_t)t * 32 + lane];
    }
#pragma unroll
    for (int off = 1; off < 32; off <<= 1) {
        float ov = __shfl_xor(v, off);
        int   oi = __shfl_xor(ix, off);
        if (ov < v || (ov == v && oi < ix)) { v = ov; ix = oi; }
    }
    const int bi = __shfl(ix, 0);
    const float* wr = w + (size_t)bi * DIM;
    const float* xr = x + (size_t)t * DIM;
    float* orow = out + (size_t)t * DIM;
    float s = 0.f;
#pragma unroll
    for (int j = 0; j < 2; ++j) {
        int d = j * 256 + lane * 4;
        float4 a = *(const float4*)(wr + d);
        float4 b = *(const float4*)(xr + d);
        *(float4*)(orow + d) = a;
        float d0 = a.x - b.x, d1 = a.y - b.y, d2 = a.z - b.z, d3 = a.w - b.w;
        s += d0 * d0 + d1 * d1 + d2 * d2 + d3 * d3;
    }
#pragma unroll
    for (int off = 1; off < 64; off <<= 1) s += __shfl_xor(s, off);
    __shared__ float ls[4];
    if (lane == 0) ls[wvi] = s;
    __syncthreads();
    if (tid == 0) lossp[blockIdx.x] = ls[0] + ls[1] + ls[2] + ls[3];
}

// ---------------- deterministic final loss reduce ----------------
__global__ void loss_final_kernel(const float* __restrict__ lossp, float* __restrict__ out) {
    __shared__ float red[256];
    float s = 0.f;
    for (int i = threadIdx.x; i < N_TOK / 4; i += 256) s += lossp[i];
    red[threadIdx.x] = s;
    __syncthreads();
    for (int st = 128; st > 0; st >>= 1) {
        if (threadIdx.x < st) red[threadIdx.x] += red[threadIdx.x + st];
        __syncthreads();
    }
    // vq_loss = (1 + BETA) * mean((q - x)^2)
    if (threadIdx.x == 0) out[(size_t)N_TOK * DIM] = red[0] * (1.25f / 8388608.f);
}

extern "C" void kernel_launch(void* const* d_in, const int* in_sizes, int n_in,
                              void* d_out, int out_size, void* d_ws, size_t ws_size,
                              hipStream_t stream) {
    const float* x = (const float*)d_in[0];   // [16384,512]
    const float* w = (const float*)d_in[1];   // [8192,512]
    float* out = (float*)d_out;               // 16384*512 + 1

    char* W = (char*)d_ws;
    u16*   xint  = (u16*)(W);                        // 32 MiB
    u16*   wint  = (u16*)(W + 33554432);             // 16 MiB
    float* wsq   = (float*)(W + 50331648);           // 32 KiB
    float* wsval = (float*)(W + 50364416);           // 2 MiB
    int*   wsidx = (int*)  (W + 52461568);           // 2 MiB
    float* lossp = (float*)(W + 54558720);           // 16 KiB

    prep_x_kernel<<<128, 256, 0, stream>>>(x, xint);
    prep_w_kernel<<<64, 256, 0, stream>>>(w, wint);
    wsq_kernel<<<N_EMB / 4, 256, 0, stream>>>(w, wsq);
    gemm_argmin_kernel<<<2048, 512, 0, stream>>>(xint, wint, wsq, wsval, wsidx);
    gather_loss_kernel<<<N_TOK / 4, 256, 0, stream>>>(w, x, wsval, wsidx, out, lossp);
    loss_final_kernel<<<1, 256, 0, stream>>>(lossp, out);
}